// Round 9
// baseline (189.876 us; speedup 1.0000x reference)
//
#include <hip/hip_runtime.h>
#include <math.h>

typedef __attribute__((ext_vector_type(8))) short short8v;
typedef __attribute__((ext_vector_type(4))) float f32x4;

// constants: 1/T and 1/(T*ln2)
#define INV_T 14.285714285714286f
#define K2C   20.60992915f
#define TIME_THR 5000000

__device__ __forceinline__ unsigned pack_bf16x2(float lo, float hi) {
  unsigned a = __float_as_uint(lo);
  unsigned b = __float_as_uint(hi);
  a = (a + 0x7FFFu + ((a >> 16) & 1u)) >> 16;
  b = (b + 0x7FFFu + ((b >> 16) & 1u)) & 0xFFFF0000u;
  return b | a;
}

__device__ __forceinline__ void gl_lds16(const void* g, void* l) {
  __builtin_amdgcn_global_load_lds(
      (const __attribute__((address_space(1))) unsigned int*)g,
      (__attribute__((address_space(3))) unsigned int*)l, 16, 0, 0);
}

// ===================== 256x256 8-phase kernel =====================
// 8 waves (2 wr x 4 wc); per-wave output 128x64 (acc[8][4] of 16x16 frags).
// LDS: lA/lB [2 dbuf][2 half][128 rows][64 k] bf16, XOR-swizzled 16B chunks
// (chunk ^= row&7) via pre-swizzled gl_lds SOURCE + swizzled ds_read.
// Stagger: next tile's {A0,B0}@phase1, A1@phase2, B1@phase3; vmcnt(4)@phase1.
// NOTE: __launch_bounds__(512) ONLY — a second arg of 2 drove the allocator
// to a 128-VGPR budget (acc alone is 128) -> 175MB scratch traffic (R8).

#define LOAD_A(P, AF)                                                     \
  {                                                                       \
    _Pragma("unroll") for (int mp = 0; mp < 2; ++mp)                      \
        _Pragma("unroll") for (int kk = 0; kk < 2; ++kk) {                \
      const int row = ((P) * 2 + mp) * 16 + lr;                           \
      const int ch = ((kk << 2) + kg) ^ (lr & 7);                         \
      AF[mp][kk] = *(const short8v*)&lA[bu][wr][row][ch << 3];            \
    }                                                                     \
  }

#define MFMA16(P, AF)                                                     \
  _Pragma("unroll") for (int kk = 0; kk < 2; ++kk)                        \
      _Pragma("unroll") for (int mp = 0; mp < 2; ++mp)                    \
          _Pragma("unroll") for (int n = 0; n < 4; ++n) acc[(P) * 2 + mp] \
              [n] = __builtin_amdgcn_mfma_f32_16x16x32_bf16(              \
                  AF[mp][kk], bf[n][kk], acc[(P) * 2 + mp][n], 0, 0, 0);

__global__ __launch_bounds__(512) void gram256(
    const unsigned short* __restrict__ descb, const int* __restrict__ seq,
    const int* __restrict__ tmid, float* __restrict__ p_se,
    float* __restrict__ p_ps, float* __restrict__ p_pc, int B, int D, int NB) {
  __shared__ __align__(16) unsigned short lA[2][2][128][64];
  __shared__ __align__(16) unsigned short lB[2][2][128][64];

  // ---- triangular block decode + XCD swizzle ----
  const int T = NB * (NB + 1) / 2;
  int t = blockIdx.x;
  if ((T & 7) == 0) t = (t & 7) * (T >> 3) + (t >> 3);
  float fn = (float)NB + 0.5f;
  int r = (int)(fn - sqrtf(fmaxf(fn * fn - 2.0f * (float)t, 0.0f)));
  if (r < 0) r = 0;
  if (r > NB - 1) r = NB - 1;
  auto Sf = [NB](int rr) { return rr * NB - ((rr * (rr - 1)) >> 1); };
  while (r > 0 && Sf(r) > t) --r;
  while (r < NB - 1 && Sf(r + 1) <= t) ++r;
  const int rb = r;
  const int cb = rb + (t - Sf(rb));
  const bool upper = (cb != rb);
  const int row0 = rb << 8;
  const int col0 = cb << 8;

  const int tid = threadIdx.x;
  const int l = tid & 63;
  const int w = tid >> 6;  // 0..7
  const int wr = w >> 2;   // 0..1
  const int wc = w & 3;    // 0..3
  const int lr = l & 15;
  const int kg = l >> 4;

  f32x4 acc[8][4];
#pragma unroll
  for (int m = 0; m < 8; ++m)
#pragma unroll
    for (int n = 0; n < 4; ++n) acc[m][n] = (f32x4){0.f, 0.f, 0.f, 0.f};

  // staging: half-tile = 128 rows x 64 k bf16 = 16KB; 512 thr x 16B x 2q.
  // granule g = q*512+tid -> row rg = q*64 + (tid>>3), slot s = tid&7;
  // linear LDS dest (rule #21), source chunk pre-swizzled c8 = s ^ (rg&7).
  const int c8 = (tid & 7) ^ ((tid >> 3) & 7);
  const int srow = tid >> 3;  // 0..63
  const int NT = D >> 6;

  auto stage_half = [&](int arr, int h, int bu_, int tt) {
    const int k0 = tt << 6;
    const int pan = arr ? col0 : row0;
    unsigned short* base = arr ? &lB[bu_][h][0][0] : &lA[bu_][h][0][0];
#pragma unroll
    for (int q = 0; q < 2; ++q) {
      const int rg = (q << 6) + srow;
      gl_lds16(descb + (size_t)(pan + (h << 7) + rg) * D + k0 + (c8 << 3),
               (char*)base + (q << 13) + tid * 16);
    }
  };

  // prologue: tile 0 fully staged (8 vmcnt events/thread)
  stage_half(0, 0, 0, 0);
  stage_half(0, 1, 0, 0);
  stage_half(1, 0, 0, 0);
  stage_half(1, 1, 0, 0);

  for (int ts = 0; ts < NT; ++ts) {
    const int bu = ts & 1;
    const int nbu = bu ^ 1;
    const bool pre = (ts + 1 < NT);
    // ---------- phase 1: stage A0,B0 of next tile; wait current tile ----------
    if (pre) {
      stage_half(0, 0, nbu, ts + 1);
      stage_half(1, 0, nbu, ts + 1);
    }
    __builtin_amdgcn_sched_barrier(0);
    if (pre)
      asm volatile("s_waitcnt vmcnt(4)" ::: "memory");
    else
      asm volatile("s_waitcnt vmcnt(0)" ::: "memory");
    __builtin_amdgcn_sched_barrier(0);
    __builtin_amdgcn_s_barrier();
    __builtin_amdgcn_sched_barrier(0);
    short8v bf[4][2];  // B-frags live across the 4 phases
#pragma unroll
    for (int n = 0; n < 4; ++n)
#pragma unroll
      for (int kk = 0; kk < 2; ++kk) {
        const int row = ((wc & 1) << 6) + (n << 4) + lr;
        const int ch = ((kk << 2) + kg) ^ (lr & 7);
        bf[n][kk] = *(const short8v*)&lB[bu][wc >> 1][row][ch << 3];
      }
    {
      short8v af[2][2];
      LOAD_A(0, af)
      __builtin_amdgcn_sched_barrier(0);
      asm volatile("s_waitcnt lgkmcnt(0)" ::: "memory");
      __builtin_amdgcn_sched_barrier(0);
      __builtin_amdgcn_s_setprio(1);
      MFMA16(0, af)
      __builtin_amdgcn_s_setprio(0);
      __builtin_amdgcn_sched_barrier(0);
      __builtin_amdgcn_s_barrier();
    }
    // ---------- phase 2: stage A1 ----------
    {
      short8v af[2][2];
      LOAD_A(1, af)
      __builtin_amdgcn_sched_barrier(0);
      if (pre) stage_half(0, 1, nbu, ts + 1);
      __builtin_amdgcn_sched_barrier(0);
      asm volatile("s_waitcnt lgkmcnt(0)" ::: "memory");
      __builtin_amdgcn_sched_barrier(0);
      __builtin_amdgcn_s_setprio(1);
      MFMA16(1, af)
      __builtin_amdgcn_s_setprio(0);
      __builtin_amdgcn_sched_barrier(0);
      __builtin_amdgcn_s_barrier();
    }
    // ---------- phase 3: stage B1 ----------
    {
      short8v af[2][2];
      LOAD_A(2, af)
      __builtin_amdgcn_sched_barrier(0);
      if (pre) stage_half(1, 1, nbu, ts + 1);
      __builtin_amdgcn_sched_barrier(0);
      asm volatile("s_waitcnt lgkmcnt(0)" ::: "memory");
      __builtin_amdgcn_sched_barrier(0);
      __builtin_amdgcn_s_setprio(1);
      MFMA16(2, af)
      __builtin_amdgcn_s_setprio(0);
      __builtin_amdgcn_sched_barrier(0);
      __builtin_amdgcn_s_barrier();
    }
    // ---------- phase 4: no staging ----------
    {
      short8v af[2][2];
      LOAD_A(3, af)
      __builtin_amdgcn_sched_barrier(0);
      asm volatile("s_waitcnt lgkmcnt(0)" ::: "memory");
      __builtin_amdgcn_sched_barrier(0);
      __builtin_amdgcn_s_setprio(1);
      MFMA16(3, af)
      __builtin_amdgcn_s_setprio(0);
      __builtin_amdgcn_sched_barrier(0);
      __builtin_amdgcn_s_barrier();
    }
  }
  __syncthreads();  // full drain before LDS reuse

  // ---- epilogue: atomic-free partials; meta loaded direct (post K-loop) ----
  float* rowred = (float*)&lA[0][0][0][0];  // [4 wc][256 rows][3]
  float* colred = (float*)&lB[0][0][0][0];  // [2 wr][256 cols][3]

  int cseq[4], ctim[4], gcol[4];
#pragma unroll
  for (int n = 0; n < 4; ++n) {
    const int cl = (wc << 6) + (n << 4) + lr;
    gcol[n] = col0 + cl;
    cseq[n] = seq[gcol[n]];
    ctim[n] = tmid[gcol[n]];
  }
  float colse[4] = {0.f, 0.f, 0.f, 0.f};
  float colpd[4] = {0.f, 0.f, 0.f, 0.f};
  float colpc[4] = {0.f, 0.f, 0.f, 0.f};

#pragma unroll
  for (int m = 0; m < 8; ++m) {
#pragma unroll
    for (int reg = 0; reg < 4; ++reg) {
      const int rl = (wr << 7) + (m << 4) + (kg << 2) + reg;
      const int growg = row0 + rl;
      const int rs = seq[growg];
      const int rt = tmid[growg];
      float se = 0.f, pd = 0.f, pcnt = 0.f;
#pragma unroll
      for (int n = 0; n < 4; ++n) {
        const float dot = acc[m][n][reg];
        const float e = exp2f(fmaf(dot, K2C, -K2C));
        const bool nd = (growg != gcol[n]);
        int dt = rt - ctim[n];
        dt = dt < 0 ? -dt : dt;
        const bool pos = nd && (rs == cseq[n]) && (dt < TIME_THR);
        const float ev = nd ? e : 0.f;
        const float dv = pos ? dot : 0.f;
        const float cv = pos ? 1.f : 0.f;
        se += ev;
        pd += dv;
        pcnt += cv;
        colse[n] += ev;
        colpd[n] += dv;
        colpc[n] += cv;
      }
#pragma unroll
      for (int s = 1; s < 16; s <<= 1) {
        se += __shfl_xor(se, s);
        pd += __shfl_xor(pd, s);
        pcnt += __shfl_xor(pcnt, s);
      }
      if (lr == 0) {
        float* rr3 = rowred + ((size_t)((wc << 8) + rl)) * 3;
        rr3[0] = se;
        rr3[1] = pd;
        rr3[2] = pcnt;
      }
    }
  }
  if (upper) {
#pragma unroll
    for (int n = 0; n < 4; ++n) {
      float cs = colse[n], cp = colpd[n], cc = colpc[n];
      cs += __shfl_xor(cs, 16);
      cp += __shfl_xor(cp, 16);
      cc += __shfl_xor(cc, 16);
      cs += __shfl_xor(cs, 32);
      cp += __shfl_xor(cp, 32);
      cc += __shfl_xor(cc, 32);
      if (l < 16) {
        const int cl = (wc << 6) + (n << 4) + lr;
        float* cr3 = colred + ((size_t)((wr << 8) + cl)) * 3;
        cr3[0] = cs;
        cr3[1] = cp;
        cr3[2] = cc;
      }
    }
  }
  __syncthreads();

  if (tid < 256) {
    float se = 0.f, pd = 0.f, pc = 0.f;
#pragma unroll
    for (int j = 0; j < 4; ++j) {
      const float* rr3 = rowred + ((size_t)((j << 8) + tid)) * 3;
      se += rr3[0];
      pd += rr3[1];
      pc += rr3[2];
    }
    const size_t o = (size_t)cb * B + row0 + tid;
    p_se[o] = se;
    p_ps[o] = pd * INV_T;
    p_pc[o] = pc;
  } else if (upper) {
    const int c = tid - 256;
    const float* c0 = colred + (size_t)c * 3;
    const float* c1 = colred + (size_t)(256 + c) * 3;
    const size_t o = (size_t)rb * B + col0 + c;
    p_se[o] = c0[0] + c1[0];
    p_ps[o] = (c0[1] + c1[1]) * INV_T;
    p_pc[o] = c0[2] + c1[2];
  }
}

// ===================== 128x128 fallback (atomic epilogue) =====================
template <int MODE>
__device__ __forceinline__ void infonce_body(
    const float* __restrict__ desc, const unsigned short* __restrict__ descb,
    const int* __restrict__ seq, const int* __restrict__ tmid,
    float* __restrict__ p_se, float* __restrict__ p_ps,
    float* __restrict__ p_pc, int B, int D, int NB) {
  __shared__ __align__(16) unsigned short lA[2][128][64];
  __shared__ __align__(16) unsigned short lB[2][128][64];
  __shared__ int mseq_r[128], mtim_r[128], mseq_c[128], mtim_c[128];

  const int T = NB * (NB + 1) / 2;
  int t = blockIdx.x;
  if ((T & 7) == 0) t = (t & 7) * (T >> 3) + (t >> 3);
  float fn = (float)NB + 0.5f;
  int r = (int)(fn - sqrtf(fmaxf(fn * fn - 2.0f * (float)t, 0.0f)));
  if (r < 0) r = 0;
  if (r > NB - 1) r = NB - 1;
  auto Sf = [NB](int rr) { return rr * NB - ((rr * (rr - 1)) >> 1); };
  while (r > 0 && Sf(r) > t) --r;
  while (r < NB - 1 && Sf(r + 1) <= t) ++r;
  const int rb = r;
  const int cb = rb + (t - Sf(rb));
  const bool upper = (cb != rb);
  const int row0 = rb * 128;
  const int col0 = cb * 128;

  const int tid = threadIdx.x;
  const int l = tid & 63;
  const int w = tid >> 6;
  const int wrow = (w >> 1) << 6;
  const int wcol = (w & 1) << 6;
  const int lr = l & 15;
  const int kg = l >> 4;

  if (tid < 128) {
    mseq_r[tid] = seq[row0 + tid];
    mtim_r[tid] = tmid[row0 + tid];
    mseq_c[tid] = seq[col0 + tid];
    mtim_c[tid] = tmid[col0 + tid];
  }

  f32x4 acc[4][4];
#pragma unroll
  for (int m = 0; m < 4; ++m)
#pragma unroll
    for (int n = 0; n < 4; ++n) acc[m][n] = (f32x4){0.f, 0.f, 0.f, 0.f};

  const int c8 = (l & 7) ^ ((l >> 3) & 7);
  const int rbase = (w << 3) + (l >> 3);
  const int sr = tid >> 3;
  const int sc = tid & 7;
  const int NT = D >> 6;

  if (MODE >= 1) {
    auto stageA = [&](int tt) {
      const int bu = tt & 1;
      const int k0 = tt << 6;
#pragma unroll
      for (int q = 0; q < 4; ++q) {
        const int rg = (q << 5) + rbase;
        gl_lds16(descb + (size_t)(row0 + rg) * D + k0 + (c8 << 3),
                 (char*)&lA[bu][0][0] + (q << 12) + (w << 10));
      }
    };
    auto stageB = [&](int tt) {
      const int bu = tt & 1;
      const int k0 = tt << 6;
#pragma unroll
      for (int q = 0; q < 4; ++q) {
        const int rg = (q << 5) + rbase;
        gl_lds16(descb + (size_t)(col0 + rg) * D + k0 + (c8 << 3),
                 (char*)&lB[bu][0][0] + (q << 12) + (w << 10));
      }
    };
    __builtin_amdgcn_sched_barrier(0);
    stageA(0);
    stageB(0);
    __builtin_amdgcn_sched_barrier(0);
    for (int ts = 0; ts < NT; ++ts) {
      const int bu = ts & 1;
      if (ts + 1 < NT) {
        stageA(ts + 1);
        __builtin_amdgcn_sched_barrier(0);
        asm volatile("s_waitcnt vmcnt(4)" ::: "memory");
      } else {
        asm volatile("s_waitcnt vmcnt(0)" ::: "memory");
      }
      __builtin_amdgcn_sched_barrier(0);
      __builtin_amdgcn_s_barrier();
      __builtin_amdgcn_sched_barrier(0);
      short8v af[2][4], bf[2][4];
#pragma unroll
      for (int kk = 0; kk < 2; ++kk) {
#pragma unroll
        for (int m = 0; m < 4; ++m) {
          const int rowa = wrow + (m << 4) + lr;
          const int ch = ((kk << 2) + kg) ^ (rowa & 7);
          af[kk][m] = *reinterpret_cast<const short8v*>(&lA[bu][rowa][ch << 3]);
        }
#pragma unroll
        for (int n = 0; n < 4; ++n) {
          const int rowb = wcol + (n << 4) + lr;
          const int ch = ((kk << 2) + kg) ^ (rowb & 7);
          bf[kk][n] = *reinterpret_cast<const short8v*>(&lB[bu][rowb][ch << 3]);
        }
      }
      __builtin_amdgcn_sched_barrier(0);
      if (ts + 1 < NT) stageB(ts + 1);
      __builtin_amdgcn_sched_barrier(0);
      asm volatile("s_waitcnt lgkmcnt(0)" ::: "memory");
      __builtin_amdgcn_sched_barrier(0);
      __builtin_amdgcn_s_setprio(1);
#pragma unroll
      for (int kk = 0; kk < 2; ++kk)
#pragma unroll
        for (int m = 0; m < 4; ++m)
#pragma unroll
          for (int n = 0; n < 4; ++n)
            acc[m][n] = __builtin_amdgcn_mfma_f32_16x16x32_bf16(
                af[kk][m], bf[kk][n], acc[m][n], 0, 0, 0);
      __builtin_amdgcn_s_setprio(0);
      __builtin_amdgcn_sched_barrier(0);
      __builtin_amdgcn_s_barrier();
    }
    __syncthreads();
  } else {
    for (int k0 = 0; k0 < D; k0 += 64) {
      __syncthreads();
#pragma unroll
      for (int p = 0; p < 4; ++p) {
        const int rr = (p << 5) + sr;
        const float* gA = desc + (size_t)(row0 + rr) * D + k0 + (sc << 3);
        const float4 fa0 = *reinterpret_cast<const float4*>(gA);
        const float4 fa1 = *reinterpret_cast<const float4*>(gA + 4);
        const float* gB = desc + (size_t)(col0 + rr) * D + k0 + (sc << 3);
        const float4 fb0 = *reinterpret_cast<const float4*>(gB);
        const float4 fb1 = *reinterpret_cast<const float4*>(gB + 4);
        uint4 wa, wb;
        wa.x = pack_bf16x2(fa0.x, fa0.y);
        wa.y = pack_bf16x2(fa0.z, fa0.w);
        wa.z = pack_bf16x2(fa1.x, fa1.y);
        wa.w = pack_bf16x2(fa1.z, fa1.w);
        wb.x = pack_bf16x2(fb0.x, fb0.y);
        wb.y = pack_bf16x2(fb0.z, fb0.w);
        wb.z = pack_bf16x2(fb1.x, fb1.y);
        wb.w = pack_bf16x2(fb1.z, fb1.w);
        const int dst = (sc ^ (rr & 7)) << 3;
        *reinterpret_cast<uint4*>(&lA[0][rr][dst]) = wa;
        *reinterpret_cast<uint4*>(&lB[0][rr][dst]) = wb;
      }
      __syncthreads();
#pragma unroll
      for (int kk = 0; kk < 2; ++kk) {
        short8v af[4], bf[4];
#pragma unroll
        for (int m = 0; m < 4; ++m) {
          const int rowa = wrow + (m << 4) + lr;
          const int ch = ((kk << 2) + kg) ^ (rowa & 7);
          af[m] = *reinterpret_cast<const short8v*>(&lA[0][rowa][ch << 3]);
        }
#pragma unroll
        for (int n = 0; n < 4; ++n) {
          const int rowb = wcol + (n << 4) + lr;
          const int ch = ((kk << 2) + kg) ^ (rowb & 7);
          bf[n] = *reinterpret_cast<const short8v*>(&lB[0][rowb][ch << 3]);
        }
#pragma unroll
        for (int m = 0; m < 4; ++m)
#pragma unroll
          for (int n = 0; n < 4; ++n)
            acc[m][n] = __builtin_amdgcn_mfma_f32_16x16x32_bf16(af[m], bf[n],
                                                                acc[m][n], 0, 0, 0);
      }
    }
    __syncthreads();
  }

  int cseq[4], ctim[4], gcol[4];
#pragma unroll
  for (int n = 0; n < 4; ++n) {
    const int cl = wcol + (n << 4) + lr;
    cseq[n] = mseq_c[cl];
    ctim[n] = mtim_c[cl];
    gcol[n] = col0 + cl;
  }
  float colse[4] = {0.f, 0.f, 0.f, 0.f};
  float colpd[4] = {0.f, 0.f, 0.f, 0.f};
  float colpc[4] = {0.f, 0.f, 0.f, 0.f};

#pragma unroll
  for (int m = 0; m < 4; ++m) {
#pragma unroll
    for (int reg = 0; reg < 4; ++reg) {
      const int rl = wrow + (m << 4) + (kg << 2) + reg;
      const int growg = row0 + rl;
      const int rs = mseq_r[rl];
      const int rt = mtim_r[rl];
      float se = 0.f, pd = 0.f, pcnt = 0.f;
#pragma unroll
      for (int n = 0; n < 4; ++n) {
        const float dot = acc[m][n][reg];
        const float e = exp2f(fmaf(dot, K2C, -K2C));
        const bool nd = (growg != gcol[n]);
        int dt = rt - ctim[n];
        dt = dt < 0 ? -dt : dt;
        const bool pos = nd && (rs == cseq[n]) && (dt < TIME_THR);
        const float ev = nd ? e : 0.f;
        const float dv = pos ? dot : 0.f;
        const float cv = pos ? 1.f : 0.f;
        se += ev;
        pd += dv;
        pcnt += cv;
        if (upper) {
          colse[n] += ev;
          colpd[n] += dv;
          colpc[n] += cv;
        }
      }
#pragma unroll
      for (int s = 1; s < 16; s <<= 1) {
        se += __shfl_xor(se, s);
        pd += __shfl_xor(pd, s);
        pcnt += __shfl_xor(pcnt, s);
      }
      if ((l & 15) == 0) {
        atomicAdd(&p_se[growg], se);
        atomicAdd(&p_ps[growg], pd * INV_T);
        atomicAdd(&p_pc[growg], pcnt);
      }
    }
  }
  if (upper) {
#pragma unroll
    for (int n = 0; n < 4; ++n) {
      float cs = colse[n], cp = colpd[n], cc = colpc[n];
      cs += __shfl_xor(cs, 16);
      cp += __shfl_xor(cp, 16);
      cc += __shfl_xor(cc, 16);
      cs += __shfl_xor(cs, 32);
      cp += __shfl_xor(cp, 32);
      cc += __shfl_xor(cc, 32);
      if (kg == 0) {
        atomicAdd(&p_se[gcol[n]], cs);
        atomicAdd(&p_ps[gcol[n]], cp * INV_T);
        atomicAdd(&p_pc[gcol[n]], cc);
      }
    }
  }
}

__global__ __launch_bounds__(256, 2) void infonce_main1(
    const float* desc, const unsigned short* descb, const int* seq,
    const int* tmid, float* p_se, float* p_ps, float* p_pc, int B, int D,
    int NB) {
  infonce_body<1>(desc, descb, seq, tmid, p_se, p_ps, p_pc, B, D, NB);
}
__global__ __launch_bounds__(256, 2) void infonce_main0(
    const float* desc, const unsigned short* descb, const int* seq,
    const int* tmid, float* p_se, float* p_ps, float* p_pc, int B, int D,
    int NB) {
  infonce_body<0>(desc, descb, seq, tmid, p_se, p_ps, p_pc, B, D, NB);
}

__global__ __launch_bounds__(256) void conv_bf16(const float* __restrict__ in,
                                                 unsigned short* __restrict__ out,
                                                 int n8) {
  const int i = blockIdx.x * 256 + threadIdx.x;
  if (i >= n8) return;
  const float4 f0 = *reinterpret_cast<const float4*>(in + (size_t)i * 8);
  const float4 f1 = *reinterpret_cast<const float4*>(in + (size_t)i * 8 + 4);
  uint4 wv;
  wv.x = pack_bf16x2(f0.x, f0.y);
  wv.y = pack_bf16x2(f0.z, f0.w);
  wv.z = pack_bf16x2(f1.x, f1.y);
  wv.w = pack_bf16x2(f1.z, f1.w);
  *reinterpret_cast<uint4*>(out + (size_t)i * 8) = wv;
}

__global__ __launch_bounds__(256) void reduce_parts(
    const float* __restrict__ p_se, const float* __restrict__ p_ps,
    const float* __restrict__ p_pc, float* __restrict__ bnum,
    float* __restrict__ bcnt, int B, int NB) {
  const int tid = threadIdx.x;
  const int row = blockIdx.x * 256 + tid;
  float se = 0.f, ps = 0.f, pc = 0.f;
  for (int j = 0; j < NB; ++j) {
    const size_t o = (size_t)j * B + row;
    se += p_se[o];
    ps += p_ps[o];
    pc += p_pc[o];
  }
  float num = pc * (logf(se) + INV_T) - ps;
  __shared__ float sn[256];
  __shared__ float sc[256];
  sn[tid] = num;
  sc[tid] = pc;
  __syncthreads();
  for (int s = 128; s > 0; s >>= 1) {
    if (tid < s) {
      sn[tid] += sn[tid + s];
      sc[tid] += sc[tid + s];
    }
    __syncthreads();
  }
  if (tid == 0) {
    bnum[blockIdx.x] = sn[0];
    bcnt[blockIdx.x] = sc[0];
  }
}

__global__ __launch_bounds__(256) void final_reduce(
    const float* __restrict__ bnum, const float* __restrict__ bcnt,
    float* __restrict__ out, int n) {
  __shared__ float sn[256];
  __shared__ float sc[256];
  const int tid = threadIdx.x;
  float a = 0.f, b = 0.f;
  for (int i = tid; i < n; i += 256) {
    a += bnum[i];
    b += bcnt[i];
  }
  sn[tid] = a;
  sc[tid] = b;
  __syncthreads();
  for (int s = 128; s > 0; s >>= 1) {
    if (tid < s) {
      sn[tid] += sn[tid + s];
      sc[tid] += sc[tid + s];
    }
    __syncthreads();
  }
  if (tid == 0) out[0] = sn[0] / fmaxf(sc[0], 1.f);
}

__global__ __launch_bounds__(1024) void infonce_finalize(
    const float* __restrict__ a_se, const float* __restrict__ a_ps,
    const float* __restrict__ a_pc, float* __restrict__ out, int B) {
  __shared__ float sn[1024];
  __shared__ float sc[1024];
  const int tid = threadIdx.x;
  float num = 0.f, cnt = 0.f;
  for (int i = tid; i < B; i += 1024) {
    const float c = a_pc[i];
    num += c * (logf(a_se[i]) + INV_T) - a_ps[i];
    cnt += c;
  }
  sn[tid] = num;
  sc[tid] = cnt;
  __syncthreads();
  for (int s = 512; s > 0; s >>= 1) {
    if (tid < s) {
      sn[tid] += sn[tid + s];
      sc[tid] += sc[tid + s];
    }
    __syncthreads();
  }
  if (tid == 0) out[0] = sn[0] / fmaxf(sc[0], 1.f);
}

extern "C" void kernel_launch(void* const* d_in, const int* in_sizes, int n_in,
                              void* d_out, int out_size, void* d_ws, size_t ws_size,
                              hipStream_t stream) {
  (void)n_in;
  (void)out_size;
  const float* desc = (const float*)d_in[0];
  const int* seq = (const int*)d_in[1];
  const int* tmid = (const int*)d_in[2];
  const int B = in_sizes[1];
  const int D = in_sizes[0] / B;
  const int n8 = B * D / 8;
  const size_t descb_bytes = (size_t)B * D * 2;

  if ((B & 255) == 0 && (D & 63) == 0) {
    const int NB = B / 256;
    const int T = NB * (NB + 1) / 2;
    const size_t parts_elems = (size_t)B * NB;
    const size_t nb1 = (size_t)B / 256;
    const size_t need = descb_bytes + 3 * parts_elems * 4 + 2 * nb1 * 4;
    if (ws_size >= need) {
      unsigned short* descb = (unsigned short*)d_ws;
      float* p_se = (float*)((char*)d_ws + descb_bytes);
      float* p_ps = p_se + parts_elems;
      float* p_pc = p_ps + parts_elems;
      float* bnum = p_pc + parts_elems;
      float* bcnt = bnum + nb1;
      conv_bf16<<<(n8 + 255) / 256, 256, 0, stream>>>(desc, descb, n8);
      gram256<<<T, 512, 0, stream>>>(descb, seq, tmid, p_se, p_ps, p_pc, B, D, NB);
      reduce_parts<<<(int)nb1, 256, 0, stream>>>(p_se, p_ps, p_pc, bnum, bcnt, B, NB);
      final_reduce<<<1, 256, 0, stream>>>(bnum, bcnt, (float*)d_out, (int)nb1);
      return;
    }
  }
  // fallbacks: 128^2 kernel with atomic epilogue
  const int NB = B / 128;
  const int T = NB * (NB + 1) / 2;
  const size_t need1 = (size_t)3 * B * 4 + descb_bytes;
  float* a_se = (float*)d_ws;
  float* a_ps = a_se + B;
  float* a_pc = a_ps + B;
  hipMemsetAsync(d_ws, 0, (size_t)3 * B * sizeof(float), stream);
  if (ws_size >= need1) {
    unsigned short* descb = (unsigned short*)((char*)d_ws + (size_t)3 * B * 4);
    conv_bf16<<<(n8 + 255) / 256, 256, 0, stream>>>(desc, descb, n8);
    infonce_main1<<<T, 256, 0, stream>>>(desc, descb, seq, tmid, a_se, a_ps,
                                         a_pc, B, D, NB);
  } else {
    infonce_main0<<<T, 256, 0, stream>>>(desc, nullptr, seq, tmid, a_se, a_ps,
                                         a_pc, B, D, NB);
  }
  infonce_finalize<<<1, 1024, 0, stream>>>(a_se, a_ps, a_pc, (float*)d_out, B);
}

// Round 10
// 184.985 us; speedup vs baseline: 1.0264x; 1.0264x over previous
//
#include <hip/hip_runtime.h>
#include <math.h>

typedef __attribute__((ext_vector_type(8))) short short8v;
typedef __attribute__((ext_vector_type(4))) float f32x4;

// constants: 1/T and 1/(T*ln2)
#define INV_T 14.285714285714286f
#define K2C   20.60992915f
#define TIME_THR 5000000

__device__ __forceinline__ unsigned pack_bf16x2(float lo, float hi) {
  unsigned a = __float_as_uint(lo);
  unsigned b = __float_as_uint(hi);
  a = (a + 0x7FFFu + ((a >> 16) & 1u)) >> 16;
  b = (b + 0x7FFFu + ((b >> 16) & 1u)) & 0xFFFF0000u;
  return b | a;
}

__device__ __forceinline__ void gl_lds16(const void* g, void* l) {
  __builtin_amdgcn_global_load_lds(
      (const __attribute__((address_space(1))) unsigned int*)g,
      (__attribute__((address_space(3))) unsigned int*)l, 16, 0, 0);
}

// ===================== 256x256 K32 triple-buffer kernel =====================
// 8 waves (2 wr x 4 wc); per-wave output 128x64 (acc[8][4] 16x16 frags).
// K-tile = 32: per tile per wave {12 ds_read_b128 -> 32 MFMA}, nothing held
// across tiles but acc (register-light: arch peak ~90 even at a 128/128
// arch/agpr split — R8/R9's 175MB scratch came from arch-side overflow).
// LDS: lA/lB [3][256][32] bf16 (96KB), XOR-swizzle slot = k-chunk ^ (row&3)
// via pre-swizzled gl_lds SOURCE + swizzled ds_read (rule #21).
// Depth-2 prefetch: during tile ts stage tile ts+2 (4 gl_lds/thread);
// entry wait vmcnt(4) drains E_ts, leaves E_{ts+1} in flight. 1 barrier/tile.

__global__ __launch_bounds__(512) __attribute__((amdgpu_waves_per_eu(2)))
void gram256(
    const unsigned short* __restrict__ descb, const int* __restrict__ seq,
    const int* __restrict__ tmid, float* __restrict__ p_se,
    float* __restrict__ p_ps, float* __restrict__ p_pc, int B, int D, int NB) {
  __shared__ __align__(16) unsigned short lA[3][256][32];
  __shared__ __align__(16) unsigned short lB[3][256][32];

  // ---- triangular block decode + XCD swizzle ----
  const int T = NB * (NB + 1) / 2;
  int t = blockIdx.x;
  if ((T & 7) == 0) t = (t & 7) * (T >> 3) + (t >> 3);
  float fn = (float)NB + 0.5f;
  int r = (int)(fn - sqrtf(fmaxf(fn * fn - 2.0f * (float)t, 0.0f)));
  if (r < 0) r = 0;
  if (r > NB - 1) r = NB - 1;
  auto Sf = [NB](int rr) { return rr * NB - ((rr * (rr - 1)) >> 1); };
  while (r > 0 && Sf(r) > t) --r;
  while (r < NB - 1 && Sf(r + 1) <= t) ++r;
  const int rb = r;
  const int cb = rb + (t - Sf(rb));
  const bool upper = (cb != rb);
  const int row0 = rb << 8;
  const int col0 = cb << 8;

  const int tid = threadIdx.x;
  const int l = tid & 63;
  const int w = tid >> 6;  // 0..7
  const int wr = w >> 2;   // 0..1
  const int wc = w & 3;    // 0..3
  const int lr = l & 15;
  const int kg = l >> 4;

  f32x4 acc[8][4];
#pragma unroll
  for (int m = 0; m < 8; ++m)
#pragma unroll
    for (int n = 0; n < 4; ++n) acc[m][n] = (f32x4){0.f, 0.f, 0.f, 0.f};

  // staging: panel = 256 rows x 32 k bf16 = 16KB = 1024 granules of 16B;
  // granule g = q*512+tid -> row = q*128 + (tid>>2), slot = tid&3.
  // Linear LDS dest; source k-chunk pre-swizzled c4 = slot ^ (row&3).
  const int c4 = (tid & 3) ^ ((tid >> 2) & 3);
  const int srow = tid >> 2;  // 0..127
  const int NT = D >> 5;      // K-tile = 32

  auto stage = [&](int arr, int bu_, int tt) {
    const int k0 = tt << 5;
    const int pan = arr ? col0 : row0;
    unsigned short* base = arr ? &lB[bu_][0][0] : &lA[bu_][0][0];
#pragma unroll
    for (int q = 0; q < 2; ++q) {
      const int rg = (q << 7) + srow;
      gl_lds16(descb + (size_t)(pan + rg) * D + k0 + (c4 << 3),
               (char*)base + (q << 13) + tid * 16);
    }
  };

  // prologue: stage tiles 0 and 1 (4 vmcnt events each)
  stage(0, 0, 0);
  stage(1, 0, 0);
  if (NT > 1) {
    stage(0, 1, 1);
    stage(1, 1, 1);
  }

  int bu = 0;
  for (int ts = 0; ts < NT; ++ts) {
    // entry: drain tile ts's stages (FIFO: they're the 4 oldest); keep
    // tile ts+1's 4 in flight.
    if (ts + 1 < NT)
      asm volatile("s_waitcnt vmcnt(4)" ::: "memory");
    else
      asm volatile("s_waitcnt vmcnt(0)" ::: "memory");
    __builtin_amdgcn_sched_barrier(0);
    __builtin_amdgcn_s_barrier();  // buf[bu] globally ready; prev reads done
    __builtin_amdgcn_sched_barrier(0);

    short8v af[8], bf[4];
#pragma unroll
    for (int m = 0; m < 8; ++m) {
      const int row = (wr << 7) + (m << 4) + lr;
      const int ch = kg ^ (row & 3);
      af[m] = *(const short8v*)&lA[bu][row][ch << 3];
    }
#pragma unroll
    for (int n = 0; n < 4; ++n) {
      const int row = (wc << 6) + (n << 4) + lr;
      const int ch = kg ^ (row & 3);
      bf[n] = *(const short8v*)&lB[bu][row][ch << 3];
    }
    __builtin_amdgcn_sched_barrier(0);
    if (ts + 2 < NT) {  // depth-2 prefetch into buf[(ts+2)%3]
      int sbu = bu + 2;
      if (sbu >= 3) sbu -= 3;
      stage(0, sbu, ts + 2);
      stage(1, sbu, ts + 2);
    }
    __builtin_amdgcn_sched_barrier(0);
    asm volatile("s_waitcnt lgkmcnt(0)" ::: "memory");
    __builtin_amdgcn_sched_barrier(0);  // rule #18: pin MFMA below the wait
    __builtin_amdgcn_s_setprio(1);
#pragma unroll
    for (int m = 0; m < 8; ++m)
#pragma unroll
      for (int n = 0; n < 4; ++n)
        acc[m][n] =
            __builtin_amdgcn_mfma_f32_16x16x32_bf16(af[m], bf[n], acc[m][n], 0, 0, 0);
    __builtin_amdgcn_s_setprio(0);
    __builtin_amdgcn_sched_barrier(0);
    bu = bu == 2 ? 0 : bu + 1;
  }
  __syncthreads();  // full drain before LDS reuse

  // ---- epilogue: atomic-free partials (identical to passing R9) ----
  float* rowred = (float*)&lA[0][0][0];  // [4 wc][256 rows][3]
  float* colred = (float*)&lB[0][0][0];  // [2 wr][256 cols][3]

  int cseq[4], ctim[4], gcol[4];
#pragma unroll
  for (int n = 0; n < 4; ++n) {
    const int cl = (wc << 6) + (n << 4) + lr;
    gcol[n] = col0 + cl;
    cseq[n] = seq[gcol[n]];
    ctim[n] = tmid[gcol[n]];
  }
  float colse[4] = {0.f, 0.f, 0.f, 0.f};
  float colpd[4] = {0.f, 0.f, 0.f, 0.f};
  float colpc[4] = {0.f, 0.f, 0.f, 0.f};

#pragma unroll
  for (int m = 0; m < 8; ++m) {
#pragma unroll
    for (int reg = 0; reg < 4; ++reg) {
      const int rl = (wr << 7) + (m << 4) + (kg << 2) + reg;
      const int growg = row0 + rl;
      const int rs = seq[growg];
      const int rt = tmid[growg];
      float se = 0.f, pd = 0.f, pcnt = 0.f;
#pragma unroll
      for (int n = 0; n < 4; ++n) {
        const float dot = acc[m][n][reg];
        const float e = exp2f(fmaf(dot, K2C, -K2C));
        const bool nd = (growg != gcol[n]);
        int dt = rt - ctim[n];
        dt = dt < 0 ? -dt : dt;
        const bool pos = nd && (rs == cseq[n]) && (dt < TIME_THR);
        const float ev = nd ? e : 0.f;
        const float dv = pos ? dot : 0.f;
        const float cv = pos ? 1.f : 0.f;
        se += ev;
        pd += dv;
        pcnt += cv;
        colse[n] += ev;
        colpd[n] += dv;
        colpc[n] += cv;
      }
#pragma unroll
      for (int s = 1; s < 16; s <<= 1) {
        se += __shfl_xor(se, s);
        pd += __shfl_xor(pd, s);
        pcnt += __shfl_xor(pcnt, s);
      }
      if (lr == 0) {
        float* rr3 = rowred + ((size_t)((wc << 8) + rl)) * 3;
        rr3[0] = se;
        rr3[1] = pd;
        rr3[2] = pcnt;
      }
    }
  }
  if (upper) {
#pragma unroll
    for (int n = 0; n < 4; ++n) {
      float cs = colse[n], cp = colpd[n], cc = colpc[n];
      cs += __shfl_xor(cs, 16);
      cp += __shfl_xor(cp, 16);
      cc += __shfl_xor(cc, 16);
      cs += __shfl_xor(cs, 32);
      cp += __shfl_xor(cp, 32);
      cc += __shfl_xor(cc, 32);
      if (l < 16) {
        const int cl = (wc << 6) + (n << 4) + lr;
        float* cr3 = colred + ((size_t)((wr << 8) + cl)) * 3;
        cr3[0] = cs;
        cr3[1] = cp;
        cr3[2] = cc;
      }
    }
  }
  __syncthreads();

  if (tid < 256) {
    float se = 0.f, pd = 0.f, pc = 0.f;
#pragma unroll
    for (int j = 0; j < 4; ++j) {
      const float* rr3 = rowred + ((size_t)((j << 8) + tid)) * 3;
      se += rr3[0];
      pd += rr3[1];
      pc += rr3[2];
    }
    const size_t o = (size_t)cb * B + row0 + tid;
    p_se[o] = se;
    p_ps[o] = pd * INV_T;
    p_pc[o] = pc;
  } else if (upper) {
    const int c = tid - 256;
    const float* c0 = colred + (size_t)c * 3;
    const float* c1 = colred + (size_t)(256 + c) * 3;
    const size_t o = (size_t)rb * B + col0 + c;
    p_se[o] = c0[0] + c1[0];
    p_ps[o] = (c0[1] + c1[1]) * INV_T;
    p_pc[o] = c0[2] + c1[2];
  }
}

// ===================== 128x128 fallback (atomic epilogue) =====================
template <int MODE>
__device__ __forceinline__ void infonce_body(
    const float* __restrict__ desc, const unsigned short* __restrict__ descb,
    const int* __restrict__ seq, const int* __restrict__ tmid,
    float* __restrict__ p_se, float* __restrict__ p_ps,
    float* __restrict__ p_pc, int B, int D, int NB) {
  __shared__ __align__(16) unsigned short lA[2][128][64];
  __shared__ __align__(16) unsigned short lB[2][128][64];
  __shared__ int mseq_r[128], mtim_r[128], mseq_c[128], mtim_c[128];

  const int T = NB * (NB + 1) / 2;
  int t = blockIdx.x;
  if ((T & 7) == 0) t = (t & 7) * (T >> 3) + (t >> 3);
  float fn = (float)NB + 0.5f;
  int r = (int)(fn - sqrtf(fmaxf(fn * fn - 2.0f * (float)t, 0.0f)));
  if (r < 0) r = 0;
  if (r > NB - 1) r = NB - 1;
  auto Sf = [NB](int rr) { return rr * NB - ((rr * (rr - 1)) >> 1); };
  while (r > 0 && Sf(r) > t) --r;
  while (r < NB - 1 && Sf(r + 1) <= t) ++r;
  const int rb = r;
  const int cb = rb + (t - Sf(rb));
  const bool upper = (cb != rb);
  const int row0 = rb * 128;
  const int col0 = cb * 128;

  const int tid = threadIdx.x;
  const int l = tid & 63;
  const int w = tid >> 6;
  const int wrow = (w >> 1) << 6;
  const int wcol = (w & 1) << 6;
  const int lr = l & 15;
  const int kg = l >> 4;

  if (tid < 128) {
    mseq_r[tid] = seq[row0 + tid];
    mtim_r[tid] = tmid[row0 + tid];
    mseq_c[tid] = seq[col0 + tid];
    mtim_c[tid] = tmid[col0 + tid];
  }

  f32x4 acc[4][4];
#pragma unroll
  for (int m = 0; m < 4; ++m)
#pragma unroll
    for (int n = 0; n < 4; ++n) acc[m][n] = (f32x4){0.f, 0.f, 0.f, 0.f};

  const int c8 = (l & 7) ^ ((l >> 3) & 7);
  const int rbase = (w << 3) + (l >> 3);
  const int sr = tid >> 3;
  const int sc = tid & 7;
  const int NT = D >> 6;

  if (MODE >= 1) {
    auto stageA = [&](int tt) {
      const int bu = tt & 1;
      const int k0 = tt << 6;
#pragma unroll
      for (int q = 0; q < 4; ++q) {
        const int rg = (q << 5) + rbase;
        gl_lds16(descb + (size_t)(row0 + rg) * D + k0 + (c8 << 3),
                 (char*)&lA[bu][0][0] + (q << 12) + (w << 10));
      }
    };
    auto stageB = [&](int tt) {
      const int bu = tt & 1;
      const int k0 = tt << 6;
#pragma unroll
      for (int q = 0; q < 4; ++q) {
        const int rg = (q << 5) + rbase;
        gl_lds16(descb + (size_t)(col0 + rg) * D + k0 + (c8 << 3),
                 (char*)&lB[bu][0][0] + (q << 12) + (w << 10));
      }
    };
    __builtin_amdgcn_sched_barrier(0);
    stageA(0);
    stageB(0);
    __builtin_amdgcn_sched_barrier(0);
    for (int ts = 0; ts < NT; ++ts) {
      const int bu = ts & 1;
      if (ts + 1 < NT) {
        stageA(ts + 1);
        __builtin_amdgcn_sched_barrier(0);
        asm volatile("s_waitcnt vmcnt(4)" ::: "memory");
      } else {
        asm volatile("s_waitcnt vmcnt(0)" ::: "memory");
      }
      __builtin_amdgcn_sched_barrier(0);
      __builtin_amdgcn_s_barrier();
      __builtin_amdgcn_sched_barrier(0);
      short8v af[2][4], bf[2][4];
#pragma unroll
      for (int kk = 0; kk < 2; ++kk) {
#pragma unroll
        for (int m = 0; m < 4; ++m) {
          const int rowa = wrow + (m << 4) + lr;
          const int ch = ((kk << 2) + kg) ^ (rowa & 7);
          af[kk][m] = *reinterpret_cast<const short8v*>(&lA[bu][rowa][ch << 3]);
        }
#pragma unroll
        for (int n = 0; n < 4; ++n) {
          const int rowb = wcol + (n << 4) + lr;
          const int ch = ((kk << 2) + kg) ^ (rowb & 7);
          bf[kk][n] = *reinterpret_cast<const short8v*>(&lB[bu][rowb][ch << 3]);
        }
      }
      __builtin_amdgcn_sched_barrier(0);
      if (ts + 1 < NT) stageB(ts + 1);
      __builtin_amdgcn_sched_barrier(0);
      asm volatile("s_waitcnt lgkmcnt(0)" ::: "memory");
      __builtin_amdgcn_sched_barrier(0);
      __builtin_amdgcn_s_setprio(1);
#pragma unroll
      for (int kk = 0; kk < 2; ++kk)
#pragma unroll
        for (int m = 0; m < 4; ++m)
#pragma unroll
          for (int n = 0; n < 4; ++n)
            acc[m][n] = __builtin_amdgcn_mfma_f32_16x16x32_bf16(
                af[kk][m], bf[kk][n], acc[m][n], 0, 0, 0);
      __builtin_amdgcn_s_setprio(0);
      __builtin_amdgcn_sched_barrier(0);
      __builtin_amdgcn_s_barrier();
    }
    __syncthreads();
  } else {
    for (int k0 = 0; k0 < D; k0 += 64) {
      __syncthreads();
#pragma unroll
      for (int p = 0; p < 4; ++p) {
        const int rr = (p << 5) + sr;
        const float* gA = desc + (size_t)(row0 + rr) * D + k0 + (sc << 3);
        const float4 fa0 = *reinterpret_cast<const float4*>(gA);
        const float4 fa1 = *reinterpret_cast<const float4*>(gA + 4);
        const float* gB = desc + (size_t)(col0 + rr) * D + k0 + (sc << 3);
        const float4 fb0 = *reinterpret_cast<const float4*>(gB);
        const float4 fb1 = *reinterpret_cast<const float4*>(gB + 4);
        uint4 wa, wb;
        wa.x = pack_bf16x2(fa0.x, fa0.y);
        wa.y = pack_bf16x2(fa0.z, fa0.w);
        wa.z = pack_bf16x2(fa1.x, fa1.y);
        wa.w = pack_bf16x2(fa1.z, fa1.w);
        wb.x = pack_bf16x2(fb0.x, fb0.y);
        wb.y = pack_bf16x2(fb0.z, fb0.w);
        wb.z = pack_bf16x2(fb1.x, fb1.y);
        wb.w = pack_bf16x2(fb1.z, fb1.w);
        const int dst = (sc ^ (rr & 7)) << 3;
        *reinterpret_cast<uint4*>(&lA[0][rr][dst]) = wa;
        *reinterpret_cast<uint4*>(&lB[0][rr][dst]) = wb;
      }
      __syncthreads();
#pragma unroll
      for (int kk = 0; kk < 2; ++kk) {
        short8v af[4], bf[4];
#pragma unroll
        for (int m = 0; m < 4; ++m) {
          const int rowa = wrow + (m << 4) + lr;
          const int ch = ((kk << 2) + kg) ^ (rowa & 7);
          af[m] = *reinterpret_cast<const short8v*>(&lA[0][rowa][ch << 3]);
        }
#pragma unroll
        for (int n = 0; n < 4; ++n) {
          const int rowb = wcol + (n << 4) + lr;
          const int ch = ((kk << 2) + kg) ^ (rowb & 7);
          bf[n] = *reinterpret_cast<const short8v*>(&lB[0][rowb][ch << 3]);
        }
#pragma unroll
        for (int m = 0; m < 4; ++m)
#pragma unroll
          for (int n = 0; n < 4; ++n)
            acc[m][n] = __builtin_amdgcn_mfma_f32_16x16x32_bf16(af[m], bf[n],
                                                                acc[m][n], 0, 0, 0);
      }
    }
    __syncthreads();
  }

  int cseq[4], ctim[4], gcol[4];
#pragma unroll
  for (int n = 0; n < 4; ++n) {
    const int cl = wcol + (n << 4) + lr;
    cseq[n] = mseq_c[cl];
    ctim[n] = mtim_c[cl];
    gcol[n] = col0 + cl;
  }
  float colse[4] = {0.f, 0.f, 0.f, 0.f};
  float colpd[4] = {0.f, 0.f, 0.f, 0.f};
  float colpc[4] = {0.f, 0.f, 0.f, 0.f};

#pragma unroll
  for (int m = 0; m < 4; ++m) {
#pragma unroll
    for (int reg = 0; reg < 4; ++reg) {
      const int rl = wrow + (m << 4) + (kg << 2) + reg;
      const int growg = row0 + rl;
      const int rs = mseq_r[rl];
      const int rt = mtim_r[rl];
      float se = 0.f, pd = 0.f, pcnt = 0.f;
#pragma unroll
      for (int n = 0; n < 4; ++n) {
        const float dot = acc[m][n][reg];
        const float e = exp2f(fmaf(dot, K2C, -K2C));
        const bool nd = (growg != gcol[n]);
        int dt = rt - ctim[n];
        dt = dt < 0 ? -dt : dt;
        const bool pos = nd && (rs == cseq[n]) && (dt < TIME_THR);
        const float ev = nd ? e : 0.f;
        const float dv = pos ? dot : 0.f;
        const float cv = pos ? 1.f : 0.f;
        se += ev;
        pd += dv;
        pcnt += cv;
        if (upper) {
          colse[n] += ev;
          colpd[n] += dv;
          colpc[n] += cv;
        }
      }
#pragma unroll
      for (int s = 1; s < 16; s <<= 1) {
        se += __shfl_xor(se, s);
        pd += __shfl_xor(pd, s);
        pcnt += __shfl_xor(pcnt, s);
      }
      if ((l & 15) == 0) {
        atomicAdd(&p_se[growg], se);
        atomicAdd(&p_ps[growg], pd * INV_T);
        atomicAdd(&p_pc[growg], pcnt);
      }
    }
  }
  if (upper) {
#pragma unroll
    for (int n = 0; n < 4; ++n) {
      float cs = colse[n], cp = colpd[n], cc = colpc[n];
      cs += __shfl_xor(cs, 16);
      cp += __shfl_xor(cp, 16);
      cc += __shfl_xor(cc, 16);
      cs += __shfl_xor(cs, 32);
      cp += __shfl_xor(cp, 32);
      cc += __shfl_xor(cc, 32);
      if (kg == 0) {
        atomicAdd(&p_se[gcol[n]], cs);
        atomicAdd(&p_ps[gcol[n]], cp * INV_T);
        atomicAdd(&p_pc[gcol[n]], cc);
      }
    }
  }
}

__global__ __launch_bounds__(256, 2) void infonce_main1(
    const float* desc, const unsigned short* descb, const int* seq,
    const int* tmid, float* p_se, float* p_ps, float* p_pc, int B, int D,
    int NB) {
  infonce_body<1>(desc, descb, seq, tmid, p_se, p_ps, p_pc, B, D, NB);
}
__global__ __launch_bounds__(256, 2) void infonce_main0(
    const float* desc, const unsigned short* descb, const int* seq,
    const int* tmid, float* p_se, float* p_ps, float* p_pc, int B, int D,
    int NB) {
  infonce_body<0>(desc, descb, seq, tmid, p_se, p_ps, p_pc, B, D, NB);
}

__global__ __launch_bounds__(256) void conv_bf16(const float* __restrict__ in,
                                                 unsigned short* __restrict__ out,
                                                 int n8) {
  const int i = blockIdx.x * 256 + threadIdx.x;
  if (i >= n8) return;
  const float4 f0 = *reinterpret_cast<const float4*>(in + (size_t)i * 8);
  const float4 f1 = *reinterpret_cast<const float4*>(in + (size_t)i * 8 + 4);
  uint4 wv;
  wv.x = pack_bf16x2(f0.x, f0.y);
  wv.y = pack_bf16x2(f0.z, f0.w);
  wv.z = pack_bf16x2(f1.x, f1.y);
  wv.w = pack_bf16x2(f1.z, f1.w);
  *reinterpret_cast<uint4*>(out + (size_t)i * 8) = wv;
}

__global__ __launch_bounds__(256) void reduce_parts(
    const float* __restrict__ p_se, const float* __restrict__ p_ps,
    const float* __restrict__ p_pc, float* __restrict__ bnum,
    float* __restrict__ bcnt, int B, int NB) {
  const int tid = threadIdx.x;
  const int row = blockIdx.x * 256 + tid;
  float se = 0.f, ps = 0.f, pc = 0.f;
  for (int j = 0; j < NB; ++j) {
    const size_t o = (size_t)j * B + row;
    se += p_se[o];
    ps += p_ps[o];
    pc += p_pc[o];
  }
  float num = pc * (logf(se) + INV_T) - ps;
  __shared__ float sn[256];
  __shared__ float sc[256];
  sn[tid] = num;
  sc[tid] = pc;
  __syncthreads();
  for (int s = 128; s > 0; s >>= 1) {
    if (tid < s) {
      sn[tid] += sn[tid + s];
      sc[tid] += sc[tid + s];
    }
    __syncthreads();
  }
  if (tid == 0) {
    bnum[blockIdx.x] = sn[0];
    bcnt[blockIdx.x] = sc[0];
  }
}

__global__ __launch_bounds__(256) void final_reduce(
    const float* __restrict__ bnum, const float* __restrict__ bcnt,
    float* __restrict__ out, int n) {
  __shared__ float sn[256];
  __shared__ float sc[256];
  const int tid = threadIdx.x;
  float a = 0.f, b = 0.f;
  for (int i = tid; i < n; i += 256) {
    a += bnum[i];
    b += bcnt[i];
  }
  sn[tid] = a;
  sc[tid] = b;
  __syncthreads();
  for (int s = 128; s > 0; s >>= 1) {
    if (tid < s) {
      sn[tid] += sn[tid + s];
      sc[tid] += sc[tid + s];
    }
    __syncthreads();
  }
  if (tid == 0) out[0] = sn[0] / fmaxf(sc[0], 1.f);
}

__global__ __launch_bounds__(1024) void infonce_finalize(
    const float* __restrict__ a_se, const float* __restrict__ a_ps,
    const float* __restrict__ a_pc, float* __restrict__ out, int B) {
  __shared__ float sn[1024];
  __shared__ float sc[1024];
  const int tid = threadIdx.x;
  float num = 0.f, cnt = 0.f;
  for (int i = tid; i < B; i += 1024) {
    const float c = a_pc[i];
    num += c * (logf(a_se[i]) + INV_T) - a_ps[i];
    cnt += c;
  }
  sn[tid] = num;
  sc[tid] = cnt;
  __syncthreads();
  for (int s = 512; s > 0; s >>= 1) {
    if (tid < s) {
      sn[tid] += sn[tid + s];
      sc[tid] += sc[tid + s];
    }
    __syncthreads();
  }
  if (tid == 0) out[0] = sn[0] / fmaxf(sc[0], 1.f);
}

extern "C" void kernel_launch(void* const* d_in, const int* in_sizes, int n_in,
                              void* d_out, int out_size, void* d_ws, size_t ws_size,
                              hipStream_t stream) {
  (void)n_in;
  (void)out_size;
  const float* desc = (const float*)d_in[0];
  const int* seq = (const int*)d_in[1];
  const int* tmid = (const int*)d_in[2];
  const int B = in_sizes[1];
  const int D = in_sizes[0] / B;
  const int n8 = B * D / 8;
  const size_t descb_bytes = (size_t)B * D * 2;

  if ((B & 255) == 0 && (D & 31) == 0) {
    const int NB = B / 256;
    const int T = NB * (NB + 1) / 2;
    const size_t parts_elems = (size_t)B * NB;
    const size_t nb1 = (size_t)B / 256;
    const size_t need = descb_bytes + 3 * parts_elems * 4 + 2 * nb1 * 4;
    if (ws_size >= need) {
      unsigned short* descb = (unsigned short*)d_ws;
      float* p_se = (float*)((char*)d_ws + descb_bytes);
      float* p_ps = p_se + parts_elems;
      float* p_pc = p_ps + parts_elems;
      float* bnum = p_pc + parts_elems;
      float* bcnt = bnum + nb1;
      conv_bf16<<<(n8 + 255) / 256, 256, 0, stream>>>(desc, descb, n8);
      gram256<<<T, 512, 0, stream>>>(descb, seq, tmid, p_se, p_ps, p_pc, B, D, NB);
      reduce_parts<<<(int)nb1, 256, 0, stream>>>(p_se, p_ps, p_pc, bnum, bcnt, B, NB);
      final_reduce<<<1, 256, 0, stream>>>(bnum, bcnt, (float*)d_out, (int)nb1);
      return;
    }
  }
  // fallbacks: 128^2 kernel with atomic epilogue
  const int NB = B / 128;
  const int T = NB * (NB + 1) / 2;
  const size_t need1 = (size_t)3 * B * 4 + descb_bytes;
  float* a_se = (float*)d_ws;
  float* a_ps = a_se + B;
  float* a_pc = a_ps + B;
  hipMemsetAsync(d_ws, 0, (size_t)3 * B * sizeof(float), stream);
  if (ws_size >= need1) {
    unsigned short* descb = (unsigned short*)((char*)d_ws + (size_t)3 * B * 4);
    conv_bf16<<<(n8 + 255) / 256, 256, 0, stream>>>(desc, descb, n8);
    infonce_main1<<<T, 256, 0, stream>>>(desc, descb, seq, tmid, a_se, a_ps,
                                         a_pc, B, D, NB);
  } else {
    infonce_main0<<<T, 256, 0, stream>>>(desc, nullptr, seq, tmid, a_se, a_ps,
                                         a_pc, B, D, NB);
  }
  infonce_finalize<<<1, 1024, 0, stream>>>(a_se, a_ps, a_pc, (float*)d_out, B);
}